// Round 1
// baseline (9.720 us; speedup 1.0000x reference)
//
#include <hip/hip_runtime.h>
#include <hip/hip_bf16.h>

// StateEncoder: the reference's conv/FC "prediction" path ends in
// softmax(axis=-1) over PRED_BITS=1 -> identically 1.0, so outputs 0..2
// (3 x (32,60,1)) are all ones. Only `changes` (32,120,1) needs compute:
//   sem_a[p][t][s] = tanh( sum_c oh_a[t,c]*sem_w_a[p,s,c] + sem_b_a[p,s] )
//   (batch-independent; the (p,B*T,4)->(32,p*T,4) reshape maps
//    dest (b2,j) -> p = b2/16, t = j % T)
//   chg_a[k][b2,j] = tanh( sem·chg_w_a[k,0:4] + action_latent[b2]·chg_w_a[k,4:8] + chg_b_a[k] )
// changes layout along j: [a1 k0 (10)] [a1 k1 (10)] [a2 k0 (50)] [a2 k1 (50)]
//
// Output layout (float32): outs0 (1920) | outs1 (1920) | outs2 (1920) | changes (3840)

#define OUT_TOTAL 9600
#define ONES_END  5760

__global__ __launch_bounds__(256) void state_encoder_kernel(
    const float* __restrict__ action_latent,  // (32,4)
    const float* __restrict__ sem_w1,         // (2,4,5)
    const float* __restrict__ sem_b1,         // (2,4)
    const float* __restrict__ chg_w1,         // (2,1,8)
    const float* __restrict__ chg_b1,         // (2,1)
    const float* __restrict__ sem_w2,         // (2,4,10)
    const float* __restrict__ sem_b2,         // (2,4)
    const float* __restrict__ chg_w2,         // (2,1,8)
    const float* __restrict__ chg_b2,         // (2,1)
    float* __restrict__ out)
{
    int o = blockIdx.x * blockDim.x + threadIdx.x;
    if (o >= OUT_TOTAL) return;

    if (o < ONES_END) {         // outs[0..2]: softmax over 1 logit == 1.0
        out[o] = 1.0f;
        return;
    }

    int idx = o - ONES_END;     // index into changes, flat (32,120)
    int b2 = idx / 120;
    int jj = idx % 120;

    int a, k, j, T;
    const float *sw, *sb, *gw, *gb;
    if (jj < 20) {
        a = 1; T = 5;
        k = jj / 10; j = jj % 10;
        sw = sem_w1; sb = sem_b1; gw = chg_w1; gb = chg_b1;
    } else {
        a = 2; T = 25;
        int r = jj - 20;
        k = r / 50; j = r % 50;
        sw = sem_w2; sb = sem_b2; gw = chg_w2; gb = chg_b2;
    }

    int p = b2 >> 4;            // predictor index from reshaped batch
    int t = j % T;              // tuple index (original batch drops out)

    float acc = gb[k];
    #pragma unroll
    for (int s = 0; s < 4; ++s) {
        float v;
        if (a == 1) {
            // one-hot selects column t of sem_w1[p,s,:]
            v = sw[(p * 4 + s) * 5 + t] + sb[p * 4 + s];
        } else {
            // t encodes (i0,i1); oh = indicator{i0} OR indicator{i1}
            int i0 = t / 5, i1 = t % 5;
            float x = sw[(p * 4 + s) * 10 + i0];
            if (i1 != i0) x += sw[(p * 4 + s) * 10 + i1];
            v = x + sb[p * 4 + s];
        }
        float sem = tanhf(v);
        acc += sem * gw[k * 8 + s];
        acc += action_latent[b2 * 4 + s] * gw[k * 8 + 4 + s];
    }
    out[o] = tanhf(acc);
}

extern "C" void kernel_launch(void* const* d_in, const int* in_sizes, int n_in,
                              void* d_out, int out_size, void* d_ws, size_t ws_size,
                              hipStream_t stream)
{
    // setup_inputs() order:
    // 0 state, 1 state_next, 2 state_tilda, 3 backgrounds, 4 action_latent,
    // 5 n_obj, 6 temp,
    // 7 conv_w1, 8 conv_b1, 9 fc2_w1, 10 fc2_b1, 11 fc3_w1, 12 fc3_b1,
    // 13 sem_w1, 14 sem_b1, 15 chg_w1, 16 chg_b1,
    // 17 conv_w2, 18 conv_b2, 19 fc2_w2, 20 fc2_b2, 21 fc3_w2, 22 fc3_b2,
    // 23 sem_w2, 24 sem_b2, 25 chg_w2, 26 chg_b2
    const float* action_latent = (const float*)d_in[4];
    const float* sem_w1 = (const float*)d_in[13];
    const float* sem_b1 = (const float*)d_in[14];
    const float* chg_w1 = (const float*)d_in[15];
    const float* chg_b1 = (const float*)d_in[16];
    const float* sem_w2 = (const float*)d_in[23];
    const float* sem_b2 = (const float*)d_in[24];
    const float* chg_w2 = (const float*)d_in[25];
    const float* chg_b2 = (const float*)d_in[26];

    float* out = (float*)d_out;

    const int threads = 256;
    const int blocks = (OUT_TOTAL + threads - 1) / threads;  // 38
    state_encoder_kernel<<<blocks, threads, 0, stream>>>(
        action_latent,
        sem_w1, sem_b1, chg_w1, chg_b1,
        sem_w2, sem_b2, chg_w2, chg_b2,
        out);
}